// Round 5
// baseline (190.786 us; speedup 1.0000x reference)
//
#include <hip/hip_runtime.h>

#define NT 10          // trees
#define NL 16          // leaves per tree
#define NN 31          // nodes per tree
#define DD 256         // hidden dim
#define G4 1024        // 4*D gates
#define NNODES (NT*NN) // 310
#define NPATH (NT*NL)  // 160
#define NB 4096
#define NROWS (NB*NT)  // 40960 output rows
#define NBLK 256

// Persistent barrier state (zero-init at module load, monotone counters —
// survives the harness 0xAA ws-poison; every call advances by exactly 5).
__device__ unsigned long long g_gen;        // barriers completed (ever)
__device__ unsigned long long g_arr[NBLK];  // per-block arrival sequence

__device__ __forceinline__ float sigf(float x)   { return 1.0f / (1.0f + __expf(-x)); }
__device__ __forceinline__ float tanh_f(float x) { return 2.0f / (1.0f + __expf(-2.0f*x)) - 1.0f; }

// Grid barrier: flag-per-block arrival (no atomic contention), block 0 polls
// all 256 flags with one coalesced agent-load per iteration, then bumps g_gen.
// Release on arrival store / acquire fence on exit give cross-XCD visibility.
__device__ __forceinline__ void gbar(int bid, int tid, unsigned long long tgt,
                                     volatile int* s_nd)
{
    __syncthreads();
    if (tid == 0)
        __hip_atomic_store(&g_arr[bid], tgt, __ATOMIC_RELEASE, __HIP_MEMORY_SCOPE_AGENT);
    if (bid == 0) {
        int nd = 1;
        while (nd) {
            if (tid == 0) *s_nd = 0;
            __syncthreads();
            unsigned long long v =
                __hip_atomic_load(&g_arr[tid], __ATOMIC_RELAXED, __HIP_MEMORY_SCOPE_AGENT);
            if (v < tgt) *s_nd = 1;
            __syncthreads();
            nd = *s_nd;
            __syncthreads();
            if (nd) __builtin_amdgcn_s_sleep(1);
        }
        __builtin_amdgcn_fence(__ATOMIC_ACQUIRE, "agent");
        if (tid == 0)
            __hip_atomic_store(&g_gen, tgt, __ATOMIC_RELEASE, __HIP_MEMORY_SCOPE_AGENT);
    } else {
        if (tid == 0) {
            while (__hip_atomic_load(&g_gen, __ATOMIC_RELAXED, __HIP_MEMORY_SCOPE_AGENT) < tgt)
                __builtin_amdgcn_s_sleep(1);
            __builtin_amdgcn_fence(__ATOMIC_ACQUIRE, "agent");
        }
        __syncthreads();
    }
}

// ---------------------------------------------------------------------------
// Single cooperative kernel: nodeproj -> 4 GEMM steps (pos0 fused) -> scatter.
// grid 256 x 256, 5 custom barriers. W_hh quarter-rows register-stationary
// across all steps; c carried in a register.
// ws: xg[310][1024] | hb0[160][256] | hb1[160][256]
// Ping-pong: step s writes hb[s&1], reads hb[(s+1)&1] (what step s-1 wrote).
// ---------------------------------------------------------------------------
__global__ __launch_bounds__(256) void k_fused(
    const float* __restrict__ cross, const float* __restrict__ emb,
    const float* __restrict__ Wih,   const float* __restrict__ Whh,
    const float* __restrict__ bih,   const float* __restrict__ bhh,
    float* __restrict__ out, float* __restrict__ ws)
{
    __shared__ float smem[20 * 260 + 20 * 4 * 64];   // 41.3 KB, reused
    __shared__ int s_nd;
    __shared__ unsigned long long s_base;

    float* xg = ws;
    float* hb[2] = { xg + NNODES * G4, xg + NNODES * G4 + NPATH * DD };

    const int tid = threadIdx.x;
    const int bid = blockIdx.x;
    if (tid == 0)
        s_base = __hip_atomic_load(&g_gen, __ATOMIC_RELAXED, __HIP_MEMORY_SCOPE_AGENT);

    // ---------- Phase 1: nodeproj. bid = (mt 0..15 [20 nodes]) x (nt 0..15).
    // Thread (kq=tid>>6, w=tid&63) holds Wih[nt*64+w][kq*64..+64] in 16 f4 regs;
    // emb tile in LDS (broadcast reads); kq-reduction via LDS.
    {
        float4* es4 = (float4*)smem;                  // rows padded to 65 f4
        float*  ps  = smem + 20 * 260;
        const int nt = bid & 15, mt = bid >> 4;
        const int kq = tid >> 6, w = tid & 63;
        const float4* W4 = (const float4*)Wih + (size_t)(nt * 64 + w) * 64 + kq * 16;
        float4 wr[16];
        #pragma unroll
        for (int j = 0; j < 16; ++j) wr[j] = W4[j];
        const float4* emb4 = (const float4*)emb;
        #pragma unroll
        for (int r = 0; r < 5; ++r) {
            int idx = tid + 256 * r;                  // 0..1279
            int m = idx >> 6, q = idx & 63;
            int n = mt * 20 + m;
            es4[m * 65 + q] = (n < NNODES) ? emb4[(size_t)n * 64 + q]
                                           : make_float4(0.f, 0.f, 0.f, 0.f);
        }
        __syncthreads();
        float acc[20];
        #pragma unroll
        for (int m = 0; m < 20; ++m) acc[m] = 0.f;
        #pragma unroll
        for (int j = 0; j < 16; ++j) {
            float4 wv = wr[j];
            #pragma unroll
            for (int m = 0; m < 20; ++m) {
                float4 h = es4[m * 65 + kq * 16 + j];
                acc[m] = fmaf(wv.x, h.x, fmaf(wv.y, h.y,
                         fmaf(wv.z, h.z, fmaf(wv.w, h.w, acc[m]))));
            }
        }
        #pragma unroll
        for (int m = 0; m < 20; ++m) ps[(m * 4 + kq) * 64 + w] = acc[m];
        __syncthreads();
        const int nl   = tid & 63;
        const int msub = tid >> 6;
        const int j    = nt * 64 + nl;
        const float bsum = bih[j] + bhh[j];
        #pragma unroll
        for (int r = 0; r < 5; ++r) {
            int m = msub * 5 + r;
            int n = mt * 20 + m;
            float s = ps[(m * 4 + 0) * 64 + nl] + ps[(m * 4 + 1) * 64 + nl]
                    + ps[(m * 4 + 2) * 64 + nl] + ps[(m * 4 + 3) * 64 + nl];
            if (n < NNODES) xg[(size_t)n * G4 + j] = s + bsum;
        }
    }

    // ---------- W_hh quarter-rows -> registers (held across all 4 steps);
    // issued before barrier 1 so the fetch overlaps the barrier wait.
    const int pg    = bid >> 4;                       // 10 paths
    const int dtile = bid & 15;                       // 16 dims
    const int kq    = tid >> 6, w = tid & 63;
    const int gate  = w >> 4, dlw = w & 15;
    const float4* Wh4 = (const float4*)Whh
        + (size_t)(gate * 256 + dtile * 16 + dlw) * 64 + kq * 16;
    float4 wreg[16];
    #pragma unroll
    for (int j = 0; j < 16; ++j) wreg[j] = Wh4[j];

    gbar(bid, tid, s_base + 1, &s_nd);

    // ---------- Phase 2: 4 GEMM steps (position 0 fused into step 1).
    {
        float4* hs4 = (float4*)smem;                  // 10 rows x 65 f4
        float*  hs  = smem;
        float*  ps  = smem + 10 * 260;
        const int p_act  = tid >> 4;                  // tid<160 active
        const int dl_act = tid & 15;
        const int d_act  = dtile * 16 + dl_act;
        const int pglob  = pg * 10 + p_act;
        const int t_act  = pglob >> 4, l_act = pglob & 15;
        float c_reg = 0.f;

        #pragma unroll
        for (int s = 1; s <= 4; ++s) {
            if (s == 1) {
                // position 0: h1 from tree-root xg row (h0=c0=0) -> LDS
                #pragma unroll
                for (int r = 0; r < 10; ++r) {
                    int t = (pg * 10 + r) >> 4;
                    const float* xr = xg + (size_t)(t * NN) * G4;
                    float c1 = sigf(xr[tid]) * tanh_f(xr[512 + tid]);
                    hs[r * 260 + tid] = sigf(xr[768 + tid]) * tanh_f(c1);
                }
                if (tid < 160) {
                    const float* xr = xg + (size_t)(t_act * NN) * G4;
                    c_reg = sigf(xr[d_act]) * tanh_f(xr[512 + d_act]);
                }
            } else {
                // read the buffer step s-1 wrote: hb[(s-1)&1] == hb[(s+1)&1]
                const float4* hin4 = (const float4*)hb[(s + 1) & 1];
                #pragma unroll
                for (int r = 0; r < 3; ++r) {
                    int idx = tid + 256 * r;
                    if (idx < 640)
                        hs4[(idx >> 6) * 65 + (idx & 63)] = hin4[(size_t)pg * 640 + idx];
                }
            }
            __syncthreads();

            float acc[10];
            #pragma unroll
            for (int p = 0; p < 10; ++p) acc[p] = 0.f;
            #pragma unroll
            for (int j = 0; j < 16; ++j) {
                float4 wv = wreg[j];
                #pragma unroll
                for (int p = 0; p < 10; ++p) {
                    float4 h = hs4[p * 65 + kq * 16 + j];      // broadcast
                    acc[p] = fmaf(wv.x, h.x, fmaf(wv.y, h.y,
                             fmaf(wv.z, h.z, fmaf(wv.w, h.w, acc[p]))));
                }
            }
            #pragma unroll
            for (int p = 0; p < 10; ++p) ps[(p * 4 + kq) * 64 + w] = acc[p];
            __syncthreads();

            if (tid < 160) {
                int off = (1 << s) - 1 + (l_act >> (4 - s));
                const float* xn = xg + (size_t)(t_act * NN + off) * G4;
                float g0 = 0.f, g1 = 0.f, g2 = 0.f, g3 = 0.f;
                #pragma unroll
                for (int q = 0; q < 4; ++q) {
                    g0 += ps[(p_act * 4 + q) * 64 +  0 + dl_act];
                    g1 += ps[(p_act * 4 + q) * 64 + 16 + dl_act];
                    g2 += ps[(p_act * 4 + q) * 64 + 32 + dl_act];
                    g3 += ps[(p_act * 4 + q) * 64 + 48 + dl_act];
                }
                float gi = g0 + xn[d_act];
                float gf = g1 + xn[256 + d_act];
                float gg = g2 + xn[512 + d_act];
                float go = g3 + xn[768 + d_act];
                float cn = sigf(gf) * c_reg + sigf(gi) * tanh_f(gg);
                c_reg = cn;
                hb[(s & 1)][(size_t)pglob * DD + d_act] = sigf(go) * tanh_f(cn);
            }
            gbar(bid, tid, s_base + 1 + s, &s_nd);
        }
    }

    // ---------- Phase 3: scatter out[b,t,:] = h_final[t*16 + leaf(b,t), :]
    // h_final = hb[0] (step 4 output). One wave per row, grid-stride.
    {
        const int gw   = bid * 4 + (tid >> 6);
        const int lane = tid & 63;
        const float4* h4 = (const float4*)hb[0];
        float4* o4 = (float4*)out;
        for (int r = gw; r < NROWS; r += 1024) {
            int b  = r / NT;
            int tt = r - b * NT;
            float v = 0.f;
            if (lane < NL) v = cross[(size_t)b * (NT * NL) + tt * NL + lane];
            unsigned long long m = __ballot(v > 0.5f);
            int leaf = m ? (int)__builtin_ctzll(m) : 0;
            int pp = tt * NL + leaf;
            o4[(size_t)r * 64 + lane] = h4[(size_t)pp * 64 + lane];
        }
    }
}

// ---------------------------------------------------------------------------
extern "C" void kernel_launch(void* const* d_in, const int* in_sizes, int n_in,
                              void* d_out, int out_size, void* d_ws, size_t ws_size,
                              hipStream_t stream)
{
    const float* cross = (const float*)d_in[0];
    const float* emb   = (const float*)d_in[1];
    const float* Wih   = (const float*)d_in[2];
    const float* Whh   = (const float*)d_in[3];
    const float* bih   = (const float*)d_in[4];
    const float* bhh   = (const float*)d_in[5];
    float* out = (float*)d_out;
    float* ws  = (float*)d_ws;

    void* args[] = { (void*)&cross, (void*)&emb, (void*)&Wih, (void*)&Whh,
                     (void*)&bih, (void*)&bhh, (void*)&out, (void*)&ws };
    hipLaunchCooperativeKernel((void*)k_fused, dim3(NBLK), dim3(256),
                               args, 0, stream);
}

// Round 6
// 159.075 us; speedup vs baseline: 1.1993x; 1.1993x over previous
//
#include <hip/hip_runtime.h>

#define NT 10          // trees
#define NL 16          // leaves per tree
#define NN 31          // nodes per tree
#define DD 256         // hidden dim
#define G4 1024        // 4*D gates
#define NNODES (NT*NN) // 310
#define NPATH (NT*NL)  // 160
#define NB 4096
#define NROWS (NB*NT)  // 40960 output rows

// Persistent sync state (zero-init at load; monotone, survives 0xAA ws-poison).
// g_L: launches completed (K1 bumps it once per call).
// g_cnt[s][pg]: arrivals for step s+1 of path-group pg; +16 per launch.
__device__ unsigned g_L;
__device__ unsigned g_cnt[3][16];

__device__ __forceinline__ float sigf(float x)   { return 1.0f / (1.0f + __expf(-x)); }
__device__ __forceinline__ float tanh_f(float x) { return 2.0f / (1.0f + __expf(-2.0f*x)) - 1.0f; }

// ---------------------------------------------------------------------------
// K1: nodeproj. xg[n][j] = emb[n].Wih[j] + bih[j] + bhh[j]
// 256 blocks = (mt 0..15 [20 nodes]) x (nt 0..15 [64 W rows]).
// Thread (kq,w) holds Wih row-quarter in 16 f4 regs; emb tile in LDS
// (broadcast reads); kq-reduction via LDS. Block 0 bumps g_L.
// ---------------------------------------------------------------------------
__global__ __launch_bounds__(256) void k_nodeproj(
    const float* __restrict__ emb, const float* __restrict__ Wih,
    const float* __restrict__ bih, const float* __restrict__ bhh,
    float* __restrict__ xg)
{
    __shared__ float smem[20 * 260 + 20 * 4 * 64];
    float4* es4 = (float4*)smem;
    float*  ps  = smem + 20 * 260;

    const int tid = threadIdx.x;
    const int nt  = blockIdx.x & 15;
    const int mt  = blockIdx.x >> 4;
    const int kq  = tid >> 6;
    const int w   = tid & 63;

    if (blockIdx.x == 0 && tid == 0)
        __hip_atomic_fetch_add(&g_L, 1u, __ATOMIC_RELAXED, __HIP_MEMORY_SCOPE_AGENT);

    const float4* W4 = (const float4*)Wih + (size_t)(nt * 64 + w) * 64 + kq * 16;
    float4 wr[16];
    #pragma unroll
    for (int j = 0; j < 16; ++j) wr[j] = W4[j];

    const float4* emb4 = (const float4*)emb;
    #pragma unroll
    for (int r = 0; r < 5; ++r) {
        int idx = tid + 256 * r;                  // 0..1279
        int m = idx >> 6, q = idx & 63;
        int n = mt * 20 + m;
        es4[m * 65 + q] = (n < NNODES) ? emb4[(size_t)n * 64 + q]
                                       : make_float4(0.f, 0.f, 0.f, 0.f);
    }
    __syncthreads();

    float acc[20];
    #pragma unroll
    for (int m = 0; m < 20; ++m) acc[m] = 0.f;
    #pragma unroll
    for (int j = 0; j < 16; ++j) {
        float4 wv = wr[j];
        #pragma unroll
        for (int m = 0; m < 20; ++m) {
            float4 h = es4[m * 65 + kq * 16 + j];
            acc[m] = fmaf(wv.x, h.x, fmaf(wv.y, h.y,
                     fmaf(wv.z, h.z, fmaf(wv.w, h.w, acc[m]))));
        }
    }
    #pragma unroll
    for (int m = 0; m < 20; ++m) ps[(m * 4 + kq) * 64 + w] = acc[m];
    __syncthreads();

    const int nl   = tid & 63;
    const int msub = tid >> 6;
    const int j    = nt * 64 + nl;
    const float bsum = bih[j] + bhh[j];
    #pragma unroll
    for (int r = 0; r < 5; ++r) {
        int m = msub * 5 + r;
        int n = mt * 20 + m;
        float s = ps[(m * 4 + 0) * 64 + nl] + ps[(m * 4 + 1) * 64 + nl]
                + ps[(m * 4 + 2) * 64 + nl] + ps[(m * 4 + 3) * 64 + nl];
        if (n < NNODES) xg[(size_t)n * G4 + j] = s + bsum;
    }
}

// ---------------------------------------------------------------------------
// K2: all 4 GEMM steps (pos0 fused). 256 blocks = (pg 0..15) x (dtile 0..15).
// Steps 1..3 sync ONLY among the 16 blocks of the same pg (cluster flags):
//   producer: h stores -> __syncthreads (drains vmcnt all waves) ->
//             tid0 release fetch_add on g_cnt[s-1][pg]  (cheap wbl2)
//   consumer: tid0 acquire-polls until count == 16*L -> __syncthreads
// Distinct buffer per step (h1g/h2g/h3g) -> no reuse/ABA; h4g row-major for K3.
// W_hh quarter-rows register-stationary across steps; c carried in register.
// ---------------------------------------------------------------------------
__global__ __launch_bounds__(256) void k_steps(
    const float* __restrict__ xg, const float* __restrict__ Whh,
    float* __restrict__ h1g, float* __restrict__ h2g,
    float* __restrict__ h3g, float* __restrict__ h4g)
{
    __shared__ float smem[10 * 260 + 10 * 4 * 64];   // h tile | partials
    float4* hs4 = (float4*)smem;
    float*  hs  = smem;
    float*  ps  = smem + 10 * 260;

    const int tid   = threadIdx.x;
    const int pg    = blockIdx.x >> 4;
    const int dtile = blockIdx.x & 15;
    const int kq    = tid >> 6;
    const int w     = tid & 63;
    const int gate  = w >> 4;
    const int dlw   = w & 15;

    unsigned tgt = 0;
    if (tid == 0)
        tgt = 16u * __hip_atomic_load(&g_L, __ATOMIC_RELAXED, __HIP_MEMORY_SCOPE_AGENT);

    const float4* Wh4 = (const float4*)Whh
        + (size_t)(gate * 256 + dtile * 16 + dlw) * 64 + kq * 16;
    float4 wreg[16];
    #pragma unroll
    for (int j = 0; j < 16; ++j) wreg[j] = Wh4[j];

    const int p_act  = tid >> 4;                 // tid<160 active
    const int dl_act = tid & 15;
    const int d_act  = dtile * 16 + dl_act;
    const int pglob  = pg * 10 + p_act;
    const int t_act  = pglob >> 4, l_act = pglob & 15;
    float c_reg = 0.f;

    float* hout[4] = { h1g, h2g, h3g, h4g };
    const float* hin[3] = { h1g, h2g, h3g };

    #pragma unroll
    for (int s = 1; s <= 4; ++s) {
        if (s == 1) {
            // position 0: h1 from tree-root xg row (h0=c0=0) -> LDS
            #pragma unroll
            for (int r = 0; r < 10; ++r) {
                int t = (pg * 10 + r) >> 4;
                const float* xr = xg + (size_t)(t * NN) * G4;
                float c1 = sigf(xr[tid]) * tanh_f(xr[512 + tid]);
                hs[r * 260 + tid] = sigf(xr[768 + tid]) * tanh_f(c1);
            }
            if (tid < 160) {
                const float* xr = xg + (size_t)(t_act * NN) * G4;
                c_reg = sigf(xr[d_act]) * tanh_f(xr[512 + d_act]);
            }
        } else {
            const float4* hin4 = (const float4*)hin[s - 2];
            #pragma unroll
            for (int r = 0; r < 3; ++r) {
                int idx = tid + 256 * r;
                if (idx < 640)
                    hs4[(idx >> 6) * 65 + (idx & 63)] = hin4[(size_t)pg * 640 + idx];
            }
        }
        __syncthreads();

        float acc[10];
        #pragma unroll
        for (int p = 0; p < 10; ++p) acc[p] = 0.f;
        #pragma unroll
        for (int j = 0; j < 16; ++j) {
            float4 wv = wreg[j];
            #pragma unroll
            for (int p = 0; p < 10; ++p) {
                float4 h = hs4[p * 65 + kq * 16 + j];      // broadcast
                acc[p] = fmaf(wv.x, h.x, fmaf(wv.y, h.y,
                         fmaf(wv.z, h.z, fmaf(wv.w, h.w, acc[p]))));
            }
        }
        #pragma unroll
        for (int p = 0; p < 10; ++p) ps[(p * 4 + kq) * 64 + w] = acc[p];
        __syncthreads();

        if (tid < 160) {
            int off = (1 << s) - 1 + (l_act >> (4 - s));
            const float* xn = xg + (size_t)(t_act * NN + off) * G4;
            float g0 = 0.f, g1 = 0.f, g2 = 0.f, g3 = 0.f;
            #pragma unroll
            for (int q = 0; q < 4; ++q) {
                g0 += ps[(p_act * 4 + q) * 64 +  0 + dl_act];
                g1 += ps[(p_act * 4 + q) * 64 + 16 + dl_act];
                g2 += ps[(p_act * 4 + q) * 64 + 32 + dl_act];
                g3 += ps[(p_act * 4 + q) * 64 + 48 + dl_act];
            }
            float gi = g0 + xn[d_act];
            float gf = g1 + xn[256 + d_act];
            float gg = g2 + xn[512 + d_act];
            float go = g3 + xn[768 + d_act];
            float cn = sigf(gf) * c_reg + sigf(gi) * tanh_f(gg);
            c_reg = cn;
            hout[s - 1][(size_t)pglob * DD + d_act] = sigf(go) * tanh_f(cn);
        }

        if (s < 4) {
            // __syncthreads drains every wave's vmcnt (stores land in L2),
            // then tid0's release-add writes back dirty L2 (tiny) + flags.
            __syncthreads();
            if (tid == 0) {
                __hip_atomic_fetch_add(&g_cnt[s - 1][pg], 1u,
                    __ATOMIC_RELEASE, __HIP_MEMORY_SCOPE_AGENT);
                while (__hip_atomic_load(&g_cnt[s - 1][pg],
                        __ATOMIC_ACQUIRE, __HIP_MEMORY_SCOPE_AGENT) < tgt)
                    __builtin_amdgcn_s_sleep(2);
            }
            __syncthreads();
        }
    }
}

// ---------------------------------------------------------------------------
// K3: scatter out[b,t,:] = h4g[t*16 + argmax(cross[b,t,:]), :]
// One wave per (b,t) row (40960 waves): ballot -> leaf, float4 row copy.
// ---------------------------------------------------------------------------
__global__ __launch_bounds__(256) void k_scatter(
    const float* __restrict__ cross, const float* __restrict__ htab,
    float* __restrict__ out)
{
    const int tid  = threadIdx.x;
    const int wave = tid >> 6;
    const int lane = tid & 63;
    const int r = blockIdx.x * 4 + wave;     // 0..40959 = b*10 + t
    const int b = r / NT;
    const int t = r - b * NT;

    float v = 0.f;
    if (lane < NL) v = cross[(size_t)b * (NT * NL) + t * NL + lane];
    unsigned long long m = __ballot(v > 0.5f);
    int leaf = m ? (int)__builtin_ctzll(m) : 0;
    int p = t * NL + leaf;

    const float4* h4 = (const float4*)htab;
    float4* o4 = (float4*)out;
    o4[(size_t)r * 64 + lane] = h4[(size_t)p * 64 + lane];
}

// ---------------------------------------------------------------------------
extern "C" void kernel_launch(void* const* d_in, const int* in_sizes, int n_in,
                              void* d_out, int out_size, void* d_ws, size_t ws_size,
                              hipStream_t stream)
{
    const float* cross = (const float*)d_in[0];
    const float* emb   = (const float*)d_in[1];
    const float* Wih   = (const float*)d_in[2];
    const float* Whh   = (const float*)d_in[3];
    const float* bih   = (const float*)d_in[4];
    const float* bhh   = (const float*)d_in[5];
    float* out = (float*)d_out;

    float* ws  = (float*)d_ws;
    float* xg  = ws;                         // 310*1024
    float* h1g = xg + NNODES * G4;           // 160*256 each
    float* h2g = h1g + NPATH * DD;
    float* h3g = h2g + NPATH * DD;
    float* h4g = h3g + NPATH * DD;

    hipLaunchKernelGGL(k_nodeproj, dim3(256), dim3(256), 0, stream,
                       emb, Wih, bih, bhh, xg);
    hipLaunchKernelGGL(k_steps, dim3(256), dim3(256), 0, stream,
                       xg, Whh, h1g, h2g, h3g, h4g);
    hipLaunchKernelGGL(k_scatter, dim3(10240), dim3(256), 0, stream,
                       cross, h4g, out);
}

// Round 7
// 128.971 us; speedup vs baseline: 1.4793x; 1.2334x over previous
//
#include <hip/hip_runtime.h>

#define NT 10          // trees
#define NL 16          // leaves per tree
#define NN 31          // nodes per tree
#define DD 256         // hidden dim
#define G4 1024        // 4*D gates
#define NNODES (NT*NN) // 310
#define NPATH (NT*NL)  // 160
#define NB 4096
#define NROWS (NB*NT)  // 40960 output rows

// Persistent sync state (zero-init at load; monotone, survives 0xAA ws-poison).
// g_L: launches completed (K1 bumps it once per call).
// g_cnt[s][pg][0]: arrivals for step s+1 of path-group pg; +16 per launch.
// Padded to 64B per pg so pollers don't share cache lines.
__device__ unsigned g_L;
__device__ unsigned g_cnt[3][16][16];

__device__ __forceinline__ float sigf(float x)   { return 1.0f / (1.0f + __expf(-x)); }
__device__ __forceinline__ float tanh_f(float x) { return 2.0f / (1.0f + __expf(-2.0f*x)) - 1.0f; }

// ---------------------------------------------------------------------------
// K1: nodeproj. xg[n][j] = emb[n].Wih[j] + bih[j] + bhh[j]
// 256 blocks = (mt 0..15 [20 nodes]) x (nt 0..15 [64 W rows]).
// Thread (kq,w) holds Wih row-quarter in 16 f4 regs; emb tile in LDS
// (broadcast reads); kq-reduction via LDS. Block 0 bumps g_L.
// ---------------------------------------------------------------------------
__global__ __launch_bounds__(256) void k_nodeproj(
    const float* __restrict__ emb, const float* __restrict__ Wih,
    const float* __restrict__ bih, const float* __restrict__ bhh,
    float* __restrict__ xg)
{
    __shared__ float smem[20 * 260 + 20 * 4 * 64];
    float4* es4 = (float4*)smem;
    float*  ps  = smem + 20 * 260;

    const int tid = threadIdx.x;
    const int nt  = blockIdx.x & 15;
    const int mt  = blockIdx.x >> 4;
    const int kq  = tid >> 6;
    const int w   = tid & 63;

    if (blockIdx.x == 0 && tid == 0)
        __hip_atomic_fetch_add(&g_L, 1u, __ATOMIC_RELAXED, __HIP_MEMORY_SCOPE_AGENT);

    const float4* W4 = (const float4*)Wih + (size_t)(nt * 64 + w) * 64 + kq * 16;
    float4 wr[16];
    #pragma unroll
    for (int j = 0; j < 16; ++j) wr[j] = W4[j];

    const float4* emb4 = (const float4*)emb;
    #pragma unroll
    for (int r = 0; r < 5; ++r) {
        int idx = tid + 256 * r;                  // 0..1279
        int m = idx >> 6, q = idx & 63;
        int n = mt * 20 + m;
        es4[m * 65 + q] = (n < NNODES) ? emb4[(size_t)n * 64 + q]
                                       : make_float4(0.f, 0.f, 0.f, 0.f);
    }
    __syncthreads();

    float acc[20];
    #pragma unroll
    for (int m = 0; m < 20; ++m) acc[m] = 0.f;
    #pragma unroll
    for (int j = 0; j < 16; ++j) {
        float4 wv = wr[j];
        #pragma unroll
        for (int m = 0; m < 20; ++m) {
            float4 h = es4[m * 65 + kq * 16 + j];
            acc[m] = fmaf(wv.x, h.x, fmaf(wv.y, h.y,
                     fmaf(wv.z, h.z, fmaf(wv.w, h.w, acc[m]))));
        }
    }
    #pragma unroll
    for (int m = 0; m < 20; ++m) ps[(m * 4 + kq) * 64 + w] = acc[m];
    __syncthreads();

    const int nl   = tid & 63;
    const int msub = tid >> 6;
    const int j    = nt * 64 + nl;
    const float bsum = bih[j] + bhh[j];
    #pragma unroll
    for (int r = 0; r < 5; ++r) {
        int m = msub * 5 + r;
        int n = mt * 20 + m;
        float s = ps[(m * 4 + 0) * 64 + nl] + ps[(m * 4 + 1) * 64 + nl]
                + ps[(m * 4 + 2) * 64 + nl] + ps[(m * 4 + 3) * 64 + nl];
        if (n < NNODES) xg[(size_t)n * G4 + j] = s + bsum;
    }
}

// ---------------------------------------------------------------------------
// K2: all 4 GEMM steps (pos0 fused). 256 blocks = (pg 0..15) x (dtile 0..15).
// Cross-block h handoff between the 16 blocks of a pg uses FINE-GRAINED
// coherence: relaxed agent-scope atomic stores/loads (per-access sc flags to
// the MALL) — NO acquire/release fences, hence no buffer_inv/wbl2 L2 flushes
// (round-6 regression). Ordering: producer stores drained by the
// vmcnt(0) inside __syncthreads, then tid0 relaxed fetch_add; consumer polls
// the flag, then issues its coherent loads. Distinct buffer per step (no ABA).
// W_hh quarter-rows register-stationary across steps; c carried in register.
// ---------------------------------------------------------------------------
__global__ __launch_bounds__(256) void k_steps(
    const float* __restrict__ xg, const float* __restrict__ Whh,
    float* __restrict__ h1g, float* __restrict__ h2g,
    float* __restrict__ h3g, float* __restrict__ h4g)
{
    __shared__ float smem[10 * 260 + 10 * 4 * 64];   // h tile | partials
    float4* hs4 = (float4*)smem;
    float*  hs  = smem;
    float*  ps  = smem + 10 * 260;

    const int tid   = threadIdx.x;
    const int pg    = blockIdx.x >> 4;
    const int dtile = blockIdx.x & 15;
    const int kq    = tid >> 6;
    const int w     = tid & 63;
    const int gate  = w >> 4;
    const int dlw   = w & 15;

    unsigned tgt = 0;
    if (tid == 0)
        tgt = 16u * __hip_atomic_load(&g_L, __ATOMIC_RELAXED, __HIP_MEMORY_SCOPE_AGENT);

    const float4* Wh4 = (const float4*)Whh
        + (size_t)(gate * 256 + dtile * 16 + dlw) * 64 + kq * 16;
    float4 wreg[16];
    #pragma unroll
    for (int j = 0; j < 16; ++j) wreg[j] = Wh4[j];

    const int p_act  = tid >> 4;                 // tid<160 active
    const int dl_act = tid & 15;
    const int d_act  = dtile * 16 + dl_act;
    const int pglob  = pg * 10 + p_act;
    const int t_act  = pglob >> 4, l_act = pglob & 15;
    float c_reg = 0.f;

    float* hout[4] = { h1g, h2g, h3g, h4g };
    const float* hin[3] = { h1g, h2g, h3g };

    #pragma unroll
    for (int s = 1; s <= 4; ++s) {
        if (s == 1) {
            // position 0: h1 from tree-root xg row (h0=c0=0) -> LDS
            #pragma unroll
            for (int r = 0; r < 10; ++r) {
                int t = (pg * 10 + r) >> 4;
                const float* xr = xg + (size_t)(t * NN) * G4;
                float c1 = sigf(xr[tid]) * tanh_f(xr[512 + tid]);
                hs[r * 260 + tid] = sigf(xr[768 + tid]) * tanh_f(c1);
            }
            if (tid < 160) {
                const float* xr = xg + (size_t)(t_act * NN) * G4;
                c_reg = sigf(xr[d_act]) * tanh_f(xr[512 + d_act]);
            }
        } else {
            // coherent (MALL) u64 loads of the previous step's h: 1280 u64
            const unsigned long long* src =
                (const unsigned long long*)(hin[s - 2] + (size_t)pg * 2560);
            float2* hs2 = (float2*)hs;
            #pragma unroll
            for (int r = 0; r < 5; ++r) {
                int i8  = tid + 256 * r;             // 0..1279
                int p   = i8 >> 7;                   // path row (128 u64/row)
                int rem = i8 & 127;
                unsigned long long raw = __hip_atomic_load(
                    src + (size_t)p * 128 + rem,
                    __ATOMIC_RELAXED, __HIP_MEMORY_SCOPE_AGENT);
                union { unsigned long long u; float2 f; } cv; cv.u = raw;
                hs2[p * 130 + rem] = cv.f;           // 260-float padded rows
            }
        }
        __syncthreads();

        float acc[10];
        #pragma unroll
        for (int p = 0; p < 10; ++p) acc[p] = 0.f;
        #pragma unroll
        for (int j = 0; j < 16; ++j) {
            float4 wv = wreg[j];
            #pragma unroll
            for (int p = 0; p < 10; ++p) {
                float4 h = hs4[p * 65 + kq * 16 + j];      // broadcast
                acc[p] = fmaf(wv.x, h.x, fmaf(wv.y, h.y,
                         fmaf(wv.z, h.z, fmaf(wv.w, h.w, acc[p]))));
            }
        }
        #pragma unroll
        for (int p = 0; p < 10; ++p) ps[(p * 4 + kq) * 64 + w] = acc[p];
        __syncthreads();

        if (tid < 160) {
            int off = (1 << s) - 1 + (l_act >> (4 - s));
            const float* xn = xg + (size_t)(t_act * NN + off) * G4;
            float g0 = 0.f, g1 = 0.f, g2 = 0.f, g3 = 0.f;
            #pragma unroll
            for (int q = 0; q < 4; ++q) {
                g0 += ps[(p_act * 4 + q) * 64 +  0 + dl_act];
                g1 += ps[(p_act * 4 + q) * 64 + 16 + dl_act];
                g2 += ps[(p_act * 4 + q) * 64 + 32 + dl_act];
                g3 += ps[(p_act * 4 + q) * 64 + 48 + dl_act];
            }
            float gi = g0 + xn[d_act];
            float gf = g1 + xn[256 + d_act];
            float gg = g2 + xn[512 + d_act];
            float go = g3 + xn[768 + d_act];
            float cn = sigf(gf) * c_reg + sigf(gi) * tanh_f(gg);
            c_reg = cn;
            float hn = sigf(go) * tanh_f(cn);
            if (s < 4) {
                // coherent store -> MALL (visible to sibling blocks)
                union { float f; unsigned u; } cv; cv.f = hn;
                __hip_atomic_store(
                    (unsigned*)(hout[s - 1] + (size_t)pglob * DD + d_act),
                    cv.u, __ATOMIC_RELAXED, __HIP_MEMORY_SCOPE_AGENT);
            } else {
                hout[3][(size_t)pglob * DD + d_act] = hn;  // launch boundary
            }
        }

        if (s < 4) {
            // __syncthreads drains vmcnt(0): coherent stores are acked at the
            // MALL before tid0's flag add issues.
            __syncthreads();
            if (tid == 0) {
                __hip_atomic_fetch_add(&g_cnt[s - 1][pg][0], 1u,
                    __ATOMIC_RELAXED, __HIP_MEMORY_SCOPE_AGENT);
                while (__hip_atomic_load(&g_cnt[s - 1][pg][0],
                        __ATOMIC_RELAXED, __HIP_MEMORY_SCOPE_AGENT) < tgt)
                    __builtin_amdgcn_s_sleep(1);
            }
            __syncthreads();
        }
    }
}

// ---------------------------------------------------------------------------
// K3: scatter out[b,t,:] = h4g[t*16 + argmax(cross[b,t,:]), :]
// One wave per (b,t) row (40960 waves): ballot -> leaf, float4 row copy.
// ---------------------------------------------------------------------------
__global__ __launch_bounds__(256) void k_scatter(
    const float* __restrict__ cross, const float* __restrict__ htab,
    float* __restrict__ out)
{
    const int tid  = threadIdx.x;
    const int wave = tid >> 6;
    const int lane = tid & 63;
    const int r = blockIdx.x * 4 + wave;     // 0..40959 = b*10 + t
    const int b = r / NT;
    const int t = r - b * NT;

    float v = 0.f;
    if (lane < NL) v = cross[(size_t)b * (NT * NL) + t * NL + lane];
    unsigned long long m = __ballot(v > 0.5f);
    int leaf = m ? (int)__builtin_ctzll(m) : 0;
    int p = t * NL + leaf;

    const float4* h4 = (const float4*)htab;
    float4* o4 = (float4*)out;
    o4[(size_t)r * 64 + lane] = h4[(size_t)p * 64 + lane];
}

// ---------------------------------------------------------------------------
extern "C" void kernel_launch(void* const* d_in, const int* in_sizes, int n_in,
                              void* d_out, int out_size, void* d_ws, size_t ws_size,
                              hipStream_t stream)
{
    const float* cross = (const float*)d_in[0];
    const float* emb   = (const float*)d_in[1];
    const float* Wih   = (const float*)d_in[2];
    const float* Whh   = (const float*)d_in[3];
    const float* bih   = (const float*)d_in[4];
    const float* bhh   = (const float*)d_in[5];
    float* out = (float*)d_out;

    float* ws  = (float*)d_ws;
    float* xg  = ws;                         // 310*1024
    float* h1g = xg + NNODES * G4;           // 160*256 each
    float* h2g = h1g + NPATH * DD;
    float* h3g = h2g + NPATH * DD;
    float* h4g = h3g + NPATH * DD;

    hipLaunchKernelGGL(k_nodeproj, dim3(256), dim3(256), 0, stream,
                       emb, Wih, bih, bhh, xg);
    hipLaunchKernelGGL(k_steps, dim3(256), dim3(256), 0, stream,
                       xg, Whh, h1g, h2g, h3g, h4g);
    hipLaunchKernelGGL(k_scatter, dim3(10240), dim3(256), 0, stream,
                       cross, h4g, out);
}

// Round 8
// 125.813 us; speedup vs baseline: 1.5164x; 1.0251x over previous
//
#include <hip/hip_runtime.h>

#define NT 10          // trees
#define NL 16          // leaves per tree
#define NN 31          // nodes per tree
#define DD 256         // hidden dim
#define G4 1024        // 4*D gates
#define NNODES (NT*NN) // 310
#define NPATH (NT*NL)  // 160
#define NB 4096
#define NROWS (NB*NT)  // 40960 output rows

// Monotone barrier counters (zero-init at load; survive 0xAA ws-poison).
// Targets are derived from each block's own fetch_add return value
// (tgt = round-up to next multiple of arrival count), so no launch counter
// is needed and graph replays are safe.
__device__ unsigned g_b0;            // full-grid barrier, +256 per launch
__device__ unsigned g_pg[3][16][32]; // per-(step,pg), +16 per launch; 128B pad

__device__ __forceinline__ float sigf(float x)   { return 1.0f / (1.0f + __expf(-x)); }
__device__ __forceinline__ float tanh_f(float x) { return 2.0f / (1.0f + __expf(-2.0f*x)) - 1.0f; }

__device__ __forceinline__ void co_store(float* p, float v) {
    union { float f; unsigned u; } c; c.f = v;
    __hip_atomic_store((unsigned*)p, c.u, __ATOMIC_RELAXED, __HIP_MEMORY_SCOPE_AGENT);
}
__device__ __forceinline__ float co_loadf(const float* p) {
    unsigned u = __hip_atomic_load((const unsigned*)p, __ATOMIC_RELAXED, __HIP_MEMORY_SCOPE_AGENT);
    union { unsigned u; float f; } c; c.u = u; return c.f;
}

// ---------------------------------------------------------------------------
// K_main: nodeproj -> B0 (full-grid flag barrier + one-time acquire inv) ->
// 4 LSTM GEMM steps with per-pg flag sync. 256 blocks x 256 threads.
// bid = (pg 0..15)*16 + (dtile 0..15) for the step phase;
// bid = (mt 0..15)*16 + (nt 0..15) for the nodeproj phase.
// ws: xg[310][1024] | h1g | h2g | h3g | h4g (each 160x256)
// ---------------------------------------------------------------------------
__global__ __launch_bounds__(256) void k_main(
    const float* __restrict__ emb, const float* __restrict__ Wih,
    const float* __restrict__ Whh, const float* __restrict__ bih,
    const float* __restrict__ bhh, float* __restrict__ xg,
    float* __restrict__ h1g, float* __restrict__ h2g,
    float* __restrict__ h3g, float* __restrict__ h4g)
{
    __shared__ float smem[20 * 260 + 20 * 4 * 64];   // 41.3 KB, reused
    const int tid = threadIdx.x;
    const int bid = blockIdx.x;

    // ================= Phase 0: nodeproj =================
    // Thread (kq,w) holds Wih[nt*64+w] quarter in 16 f4 regs; emb tile in LDS.
    // xg stores are COHERENT (MALL write-through) - consumed cross-block.
    {
        float4* es4 = (float4*)smem;                  // rows padded to 65 f4
        float*  ps  = smem + 20 * 260;
        const int nt = bid & 15, mt = bid >> 4;
        const int kq = tid >> 6, w = tid & 63;
        const float4* W4 = (const float4*)Wih + (size_t)(nt * 64 + w) * 64 + kq * 16;
        float4 wr[16];
        #pragma unroll
        for (int j = 0; j < 16; ++j) wr[j] = W4[j];
        const float4* emb4 = (const float4*)emb;
        #pragma unroll
        for (int r = 0; r < 5; ++r) {
            int idx = tid + 256 * r;                  // 0..1279
            int m = idx >> 6, q = idx & 63;
            int n = mt * 20 + m;
            es4[m * 65 + q] = (n < NNODES) ? emb4[(size_t)n * 64 + q]
                                           : make_float4(0.f, 0.f, 0.f, 0.f);
        }
        __syncthreads();
        float acc[20];
        #pragma unroll
        for (int m = 0; m < 20; ++m) acc[m] = 0.f;
        #pragma unroll
        for (int j = 0; j < 16; ++j) {
            float4 wv = wr[j];
            #pragma unroll
            for (int m = 0; m < 20; ++m) {
                float4 h = es4[m * 65 + kq * 16 + j];
                acc[m] = fmaf(wv.x, h.x, fmaf(wv.y, h.y,
                         fmaf(wv.z, h.z, fmaf(wv.w, h.w, acc[m]))));
            }
        }
        #pragma unroll
        for (int m = 0; m < 20; ++m) ps[(m * 4 + kq) * 64 + w] = acc[m];
        __syncthreads();
        const int nl   = tid & 63;
        const int msub = tid >> 6;
        const int j    = nt * 64 + nl;
        const float bsum = bih[j] + bhh[j];
        #pragma unroll
        for (int r = 0; r < 5; ++r) {
            int m = msub * 5 + r;
            int n = mt * 20 + m;
            float s = ps[(m * 4 + 0) * 64 + nl] + ps[(m * 4 + 1) * 64 + nl]
                    + ps[(m * 4 + 2) * 64 + nl] + ps[(m * 4 + 3) * 64 + nl];
            if (n < NNODES) co_store(&xg[(size_t)n * G4 + j], s + bsum);
        }
    }

    // ================= B0: full-grid barrier =================
    // syncthreads drains the coherent xg stores (vmcnt0 at MALL) before the
    // flag add. Whh register prefetch overlaps the poll. One acquire fence
    // per block afterwards (single buffer_inv) makes MALL-fresh xg visible
    // to normal cached loads for the rest of the kernel.
    __syncthreads();
    unsigned v0 = 0;
    if (tid == 0)
        v0 = __hip_atomic_fetch_add(&g_b0, 1u, __ATOMIC_RELAXED, __HIP_MEMORY_SCOPE_AGENT);

    const int pg    = bid >> 4;                       // 10 paths
    const int dtile = bid & 15;                       // 16 dims
    const int kq    = tid >> 6, w = tid & 63;
    const int gate  = w >> 4, dlw = w & 15;
    const float4* Wh4 = (const float4*)Whh
        + (size_t)(gate * 256 + dtile * 16 + dlw) * 64 + kq * 16;
    float4 wreg[16];
    #pragma unroll
    for (int j = 0; j < 16; ++j) wreg[j] = Wh4[j];    // in flight during poll

    if (tid == 0) {
        unsigned t0 = ((v0 >> 8) + 1) << 8;
        while (__hip_atomic_load(&g_b0, __ATOMIC_RELAXED, __HIP_MEMORY_SCOPE_AGENT) < t0)
            __builtin_amdgcn_s_sleep(1);
    }
    __syncthreads();
    __builtin_amdgcn_fence(__ATOMIC_ACQUIRE, "agent");  // one-time L1/L2 inv

    // ================= Phase 1: 4 GEMM steps =================
    {
        float4* hs4 = (float4*)smem;                  // 10 rows x 65 f4
        float*  hs  = smem;
        float*  ps  = smem + 10 * 260;
        const int p_act  = tid >> 4;                  // tid<160 active
        const int dl_act = tid & 15;
        const int d_act  = dtile * 16 + dl_act;
        const int pglob  = pg * 10 + p_act;
        const int t_act  = pglob >> 4, l_act = pglob & 15;
        float c_reg = 0.f;

        float* hout[4] = { h1g, h2g, h3g, h4g };
        const float* hin[3] = { h1g, h2g, h3g };

        #pragma unroll
        for (int s = 1; s <= 4; ++s) {
            if (s == 1) {
                // position 0: h from tree-root xg row (h0=c0=0) -> LDS
                #pragma unroll
                for (int r = 0; r < 10; ++r) {
                    int t = (pg * 10 + r) >> 4;
                    const float* xr = xg + (size_t)(t * NN) * G4;
                    float c1 = sigf(xr[tid]) * tanh_f(xr[512 + tid]);
                    hs[r * 260 + tid] = sigf(xr[768 + tid]) * tanh_f(c1);
                }
                if (tid < 160) {
                    const float* xr = xg + (size_t)(t_act * NN) * G4;
                    c_reg = sigf(xr[d_act]) * tanh_f(xr[512 + d_act]);
                }
            } else {
                // coherent (MALL) u64 loads of the previous step's h
                const unsigned long long* src =
                    (const unsigned long long*)(hin[s - 2] + (size_t)pg * 2560);
                float2* hs2 = (float2*)hs;
                #pragma unroll
                for (int r = 0; r < 5; ++r) {
                    int i8  = tid + 256 * r;             // 0..1279
                    int p   = i8 >> 7;
                    int rem = i8 & 127;
                    unsigned long long raw = __hip_atomic_load(
                        src + (size_t)p * 128 + rem,
                        __ATOMIC_RELAXED, __HIP_MEMORY_SCOPE_AGENT);
                    union { unsigned long long u; float2 f; } cv; cv.u = raw;
                    hs2[p * 130 + rem] = cv.f;
                }
            }
            __syncthreads();

            // xn gate biases loaded EARLY (hidden under the FMA block)
            int off = (1 << s) - 1 + (l_act >> (4 - s));
            const float* xn = xg + (size_t)(t_act * NN + off) * G4;
            float x0 = 0.f, x1 = 0.f, x2 = 0.f, x3 = 0.f;
            if (tid < 160) {
                x0 = xn[d_act];       x1 = xn[256 + d_act];
                x2 = xn[512 + d_act]; x3 = xn[768 + d_act];
            }

            float acc[10];
            #pragma unroll
            for (int p = 0; p < 10; ++p) acc[p] = 0.f;
            #pragma unroll
            for (int j = 0; j < 16; ++j) {
                float4 wv = wreg[j];
                #pragma unroll
                for (int p = 0; p < 10; ++p) {
                    float4 h = hs4[p * 65 + kq * 16 + j];      // broadcast
                    acc[p] = fmaf(wv.x, h.x, fmaf(wv.y, h.y,
                             fmaf(wv.z, h.z, fmaf(wv.w, h.w, acc[p]))));
                }
            }
            #pragma unroll
            for (int p = 0; p < 10; ++p) ps[(p * 4 + kq) * 64 + w] = acc[p];
            __syncthreads();

            if (tid < 160) {
                float g0 = 0.f, g1 = 0.f, g2 = 0.f, g3 = 0.f;
                #pragma unroll
                for (int q = 0; q < 4; ++q) {
                    g0 += ps[(p_act * 4 + q) * 64 +  0 + dl_act];
                    g1 += ps[(p_act * 4 + q) * 64 + 16 + dl_act];
                    g2 += ps[(p_act * 4 + q) * 64 + 32 + dl_act];
                    g3 += ps[(p_act * 4 + q) * 64 + 48 + dl_act];
                }
                float gi = g0 + x0;
                float gf = g1 + x1;
                float gg = g2 + x2;
                float go = g3 + x3;
                float cn = sigf(gf) * c_reg + sigf(gi) * tanh_f(gg);
                c_reg = cn;
                float hn = sigf(go) * tanh_f(cn);
                if (s < 4) {
                    co_store(hout[s - 1] + (size_t)pglob * DD + d_act, hn);
                } else {
                    hout[3][(size_t)pglob * DD + d_act] = hn;  // launch boundary
                }
            }

            if (s < 4) {
                // drain coherent h stores, then per-pg flag barrier (16 arrivals)
                __syncthreads();
                if (tid == 0) {
                    unsigned v = __hip_atomic_fetch_add(&g_pg[s - 1][pg][0], 1u,
                        __ATOMIC_RELAXED, __HIP_MEMORY_SCOPE_AGENT);
                    unsigned t = ((v >> 4) + 1) << 4;
                    while (__hip_atomic_load(&g_pg[s - 1][pg][0],
                            __ATOMIC_RELAXED, __HIP_MEMORY_SCOPE_AGENT) < t)
                        __builtin_amdgcn_s_sleep(1);
                }
                __syncthreads();
            }
        }
    }
}

// ---------------------------------------------------------------------------
// K_scatter: out[b,t,:] = h4g[t*16 + argmax(cross[b,t,:]), :]
// One wave per (b,t) row (40960 waves): ballot -> leaf, float4 row copy.
// Normal cached loads (launch boundary = producer/consumer fence).
// ---------------------------------------------------------------------------
__global__ __launch_bounds__(256) void k_scatter(
    const float* __restrict__ cross, const float* __restrict__ htab,
    float* __restrict__ out)
{
    const int tid  = threadIdx.x;
    const int wave = tid >> 6;
    const int lane = tid & 63;
    const int r = blockIdx.x * 4 + wave;     // 0..40959 = b*10 + t
    const int b = r / NT;
    const int t = r - b * NT;

    float v = 0.f;
    if (lane < NL) v = cross[(size_t)b * (NT * NL) + t * NL + lane];
    unsigned long long m = __ballot(v > 0.5f);
    int leaf = m ? (int)__builtin_ctzll(m) : 0;
    int p = t * NL + leaf;

    const float4* h4 = (const float4*)htab;
    float4* o4 = (float4*)out;
    o4[(size_t)r * 64 + lane] = h4[(size_t)p * 64 + lane];
}

// ---------------------------------------------------------------------------
extern "C" void kernel_launch(void* const* d_in, const int* in_sizes, int n_in,
                              void* d_out, int out_size, void* d_ws, size_t ws_size,
                              hipStream_t stream)
{
    const float* cross = (const float*)d_in[0];
    const float* emb   = (const float*)d_in[1];
    const float* Wih   = (const float*)d_in[2];
    const float* Whh   = (const float*)d_in[3];
    const float* bih   = (const float*)d_in[4];
    const float* bhh   = (const float*)d_in[5];
    float* out = (float*)d_out;

    float* ws  = (float*)d_ws;
    float* xg  = ws;                         // 310*1024
    float* h1g = xg + NNODES * G4;           // 160*256 each
    float* h2g = h1g + NPATH * DD;
    float* h3g = h2g + NPATH * DD;
    float* h4g = h3g + NPATH * DD;

    hipLaunchKernelGGL(k_main, dim3(256), dim3(256), 0, stream,
                       emb, Wih, Whh, bih, bhh, xg, h1g, h2g, h3g, h4g);
    hipLaunchKernelGGL(k_scatter, dim3(10240), dim3(256), 0, stream,
                       cross, h4g, out);
}

// Round 9
// 118.117 us; speedup vs baseline: 1.6152x; 1.0652x over previous
//
#include <hip/hip_runtime.h>

#define NT 10          // trees
#define NL 16          // leaves per tree
#define NN 31          // nodes per tree
#define DD 256         // hidden dim
#define G4 1024        // 4*D gates
#define NNODES (NT*NN) // 310
#define NPATH (NT*NL)  // 160
#define NB 4096
#define NROWS (NB*NT)  // 40960 output rows

// Monotone per-(step,pg) arrival counters (zero-init at load; survive 0xAA
// ws-poison; +16 per launch each). Base is read at kernel entry (stable:
// nobody can add to ANY step flag until this block participates in barriers),
// so targets are launch-generation-free and graph-replay-safe. 128B padding.
__device__ unsigned g_pg[3][16][32];

__device__ __forceinline__ float sigf(float x)   { return 1.0f / (1.0f + __expf(-x)); }
__device__ __forceinline__ float tanh_f(float x) { return 2.0f / (1.0f + __expf(-2.0f*x)) - 1.0f; }

__device__ __forceinline__ void co_store(float* p, float v) {
    union { float f; unsigned u; } c; c.f = v;
    __hip_atomic_store((unsigned*)p, c.u, __ATOMIC_RELAXED, __HIP_MEMORY_SCOPE_AGENT);
}

// ---------------------------------------------------------------------------
// K1: nodeproj. xg[n][j] = emb[n].Wih[j] + bih[j] + bhh[j]
// 256 blocks = (mt 0..15 [20 nodes]) x (nt 0..15 [64 W rows]). Proven ~3 us.
// Plain stores; the launch boundary publishes xg to K2.
// ---------------------------------------------------------------------------
__global__ __launch_bounds__(256) void k_nodeproj(
    const float* __restrict__ emb, const float* __restrict__ Wih,
    const float* __restrict__ bih, const float* __restrict__ bhh,
    float* __restrict__ xg)
{
    __shared__ float smem[20 * 260 + 20 * 4 * 64];
    float4* es4 = (float4*)smem;
    float*  ps  = smem + 20 * 260;

    const int tid = threadIdx.x;
    const int nt  = blockIdx.x & 15;
    const int mt  = blockIdx.x >> 4;
    const int kq  = tid >> 6;
    const int w   = tid & 63;

    const float4* W4 = (const float4*)Wih + (size_t)(nt * 64 + w) * 64 + kq * 16;
    float4 wr[16];
    #pragma unroll
    for (int j = 0; j < 16; ++j) wr[j] = W4[j];

    const float4* emb4 = (const float4*)emb;
    #pragma unroll
    for (int r = 0; r < 5; ++r) {
        int idx = tid + 256 * r;                  // 0..1279
        int m = idx >> 6, q = idx & 63;
        int n = mt * 20 + m;
        es4[m * 65 + q] = (n < NNODES) ? emb4[(size_t)n * 64 + q]
                                       : make_float4(0.f, 0.f, 0.f, 0.f);
    }
    __syncthreads();

    float acc[20];
    #pragma unroll
    for (int m = 0; m < 20; ++m) acc[m] = 0.f;
    #pragma unroll
    for (int j = 0; j < 16; ++j) {
        float4 wv = wr[j];
        #pragma unroll
        for (int m = 0; m < 20; ++m) {
            float4 h = es4[m * 65 + kq * 16 + j];
            acc[m] = fmaf(wv.x, h.x, fmaf(wv.y, h.y,
                     fmaf(wv.z, h.z, fmaf(wv.w, h.w, acc[m]))));
        }
    }
    #pragma unroll
    for (int m = 0; m < 20; ++m) ps[(m * 4 + kq) * 64 + w] = acc[m];
    __syncthreads();

    const int nl   = tid & 63;
    const int msub = tid >> 6;
    const int j    = nt * 64 + nl;
    const float bsum = bih[j] + bhh[j];
    #pragma unroll
    for (int r = 0; r < 5; ++r) {
        int m = msub * 5 + r;
        int n = mt * 20 + m;
        float s = ps[(m * 4 + 0) * 64 + nl] + ps[(m * 4 + 1) * 64 + nl]
                + ps[(m * 4 + 2) * 64 + nl] + ps[(m * 4 + 3) * 64 + nl];
        if (n < NNODES) xg[(size_t)n * G4 + j] = s + bsum;
    }
}

// ---------------------------------------------------------------------------
// K2: 4 LSTM GEMM steps. 256 blocks = (pg 0..15 [10 paths]) x (dtile 0..15).
// All xg inputs (pos-0 root rows, deduped to <=2 trees; xn biases for all 4
// steps) prefetched to REGISTERS at entry -> post-barrier work touches only
// LDS/regs/h-exchange. h handoff: relaxed agent-scope (MALL) stores/loads,
// no fences. Barrier: producer __syncthreads (drains co_stores) + tid0
// relaxed fetch_add; consumers = ALL waves tight-poll flag >= base+16.
// W_hh quarter-rows register-stationary across all steps; c in a register.
// ---------------------------------------------------------------------------
__global__ __launch_bounds__(256) void k_steps(
    const float* __restrict__ xg, const float* __restrict__ Whh,
    float* __restrict__ h1g, float* __restrict__ h2g,
    float* __restrict__ h3g, float* __restrict__ h4g)
{
    __shared__ float smem[10 * 260 + 10 * 4 * 64];   // h tile | partials
    float4* hs4 = (float4*)smem;
    float*  hs  = smem;
    float*  ps  = smem + 10 * 260;

    const int tid   = threadIdx.x;
    const int pg    = blockIdx.x >> 4;
    const int dtile = blockIdx.x & 15;
    const int kq    = tid >> 6;
    const int w     = tid & 63;
    const int gate  = w >> 4;
    const int dlw   = w & 15;

    // Stable pre-arrival base for all three barrier targets (see decl note).
    const unsigned base = __hip_atomic_load(&g_pg[2][pg][0],
        __ATOMIC_RELAXED, __HIP_MEMORY_SCOPE_AGENT);

    // ---- Entry prefetch #1: pos-0 root rows (only 1-2 distinct trees/pg)
    const int t0 = (pg * 10) >> 4;
    const int t1 = (pg * 10 + 9) >> 4;
    const float* xr0 = xg + (size_t)(t0 * NN) * G4;
    const float* xr1 = xg + (size_t)(t1 * NN) * G4;
    float ri0 = xr0[tid], rg0 = xr0[512 + tid], ro0 = xr0[768 + tid];
    float ri1 = xr1[tid], rg1 = xr1[512 + tid], ro1 = xr1[768 + tid];

    // ---- Entry prefetch #2: xn gate biases for steps 1..4 (tid<160)
    const int p_act  = tid >> 4;
    const int dl_act = tid & 15;
    const int d_act  = dtile * 16 + dl_act;
    const int pglob  = pg * 10 + p_act;
    const int t_act  = pglob >> 4, l_act = pglob & 15;
    float xnv[4][4];
    float rc_i = 0.f, rc_g = 0.f;
    if (tid < 160) {
        #pragma unroll
        for (int s = 1; s <= 4; ++s) {
            int off = (1 << s) - 1 + (l_act >> (4 - s));
            const float* xn = xg + (size_t)(t_act * NN + off) * G4;
            xnv[s - 1][0] = xn[d_act];
            xnv[s - 1][1] = xn[256 + d_act];
            xnv[s - 1][2] = xn[512 + d_act];
            xnv[s - 1][3] = xn[768 + d_act];
        }
        const float* xr = xg + (size_t)(t_act * NN) * G4;
        rc_i = xr[d_act]; rc_g = xr[512 + d_act];
    }

    // ---- Entry prefetch #3: W_hh quarter-rows (stationary all 4 steps)
    const float4* Wh4 = (const float4*)Whh
        + (size_t)(gate * 256 + dtile * 16 + dlw) * 64 + kq * 16;
    float4 wreg[16];
    #pragma unroll
    for (int j = 0; j < 16; ++j) wreg[j] = Wh4[j];

    float c_reg = 0.f;
    if (tid < 160) c_reg = sigf(rc_i) * tanh_f(rc_g);   // c after pos-0

    // pos-0 h into LDS (h0=c0=0): two candidate values, select per row
    {
        float c1a = sigf(ri0) * tanh_f(rg0);
        float h1a = sigf(ro0) * tanh_f(c1a);
        float c1b = sigf(ri1) * tanh_f(rg1);
        float h1b = sigf(ro1) * tanh_f(c1b);
        #pragma unroll
        for (int r = 0; r < 10; ++r) {
            int t = (pg * 10 + r) >> 4;
            hs[r * 260 + tid] = (t == t0) ? h1a : h1b;
        }
    }
    __syncthreads();

    float* hout[4] = { h1g, h2g, h3g, h4g };
    const float* hin[3] = { h1g, h2g, h3g };

    #pragma unroll
    for (int s = 1; s <= 4; ++s) {
        if (s > 1) {
            // all-wave tight poll on the step-(s-1) flag
            const unsigned tgt = base + 16u;
            while (__hip_atomic_load(&g_pg[s - 2][pg][0],
                    __ATOMIC_RELAXED, __HIP_MEMORY_SCOPE_AGENT) < tgt) {}
            // stage prev h: 5 in-flight MALL u64 loads -> regs -> LDS
            const unsigned long long* src =
                (const unsigned long long*)(hin[s - 2] + (size_t)pg * 2560);
            unsigned long long raw[5];
            #pragma unroll
            for (int r = 0; r < 5; ++r) {
                int i8 = tid + 256 * r;              // 0..1279
                raw[r] = __hip_atomic_load(
                    src + (size_t)(i8 >> 7) * 128 + (i8 & 127),
                    __ATOMIC_RELAXED, __HIP_MEMORY_SCOPE_AGENT);
            }
            float2* hs2 = (float2*)hs;
            #pragma unroll
            for (int r = 0; r < 5; ++r) {
                int i8 = tid + 256 * r;
                union { unsigned long long u; float2 f; } cv; cv.u = raw[r];
                hs2[(i8 >> 7) * 130 + (i8 & 127)] = cv.f;
            }
            __syncthreads();
        }

        float acc[10];
        #pragma unroll
        for (int p = 0; p < 10; ++p) acc[p] = 0.f;
        #pragma unroll
        for (int j = 0; j < 16; ++j) {
            float4 wv = wreg[j];
            #pragma unroll
            for (int p = 0; p < 10; ++p) {
                float4 h = hs4[p * 65 + kq * 16 + j];      // broadcast
                acc[p] = fmaf(wv.x, h.x, fmaf(wv.y, h.y,
                         fmaf(wv.z, h.z, fmaf(wv.w, h.w, acc[p]))));
            }
        }
        #pragma unroll
        for (int p = 0; p < 10; ++p) ps[(p * 4 + kq) * 64 + w] = acc[p];
        __syncthreads();

        if (tid < 160) {
            float g0 = 0.f, g1 = 0.f, g2 = 0.f, g3 = 0.f;
            #pragma unroll
            for (int q = 0; q < 4; ++q) {
                g0 += ps[(p_act * 4 + q) * 64 +  0 + dl_act];
                g1 += ps[(p_act * 4 + q) * 64 + 16 + dl_act];
                g2 += ps[(p_act * 4 + q) * 64 + 32 + dl_act];
                g3 += ps[(p_act * 4 + q) * 64 + 48 + dl_act];
            }
            float gi = g0 + xnv[s - 1][0];
            float gf = g1 + xnv[s - 1][1];
            float gg = g2 + xnv[s - 1][2];
            float go = g3 + xnv[s - 1][3];
            float cn = sigf(gf) * c_reg + sigf(gi) * tanh_f(gg);
            c_reg = cn;
            float hn = sigf(go) * tanh_f(cn);
            if (s < 4) co_store(hout[s - 1] + (size_t)pglob * DD + d_act, hn);
            else       hout[3][(size_t)pglob * DD + d_act] = hn;  // launch bdry
        }

        if (s < 4) {
            // drain this block's coherent h stores, then signal arrival
            __syncthreads();
            if (tid == 0)
                __hip_atomic_fetch_add(&g_pg[s - 1][pg][0], 1u,
                    __ATOMIC_RELAXED, __HIP_MEMORY_SCOPE_AGENT);
            // NOTE: no trailing __syncthreads — each wave self-polls next iter;
            // LDS hs reuse is safe (next write is preceded by poll+stage+sync).
        }
    }
}

// ---------------------------------------------------------------------------
// K3: scatter out[b,t,:] = h4g[t*16 + argmax(cross[b,t,:]), :]
// One wave per (b,t) row (40960 waves): ballot -> leaf, float4 row copy.
// ---------------------------------------------------------------------------
__global__ __launch_bounds__(256) void k_scatter(
    const float* __restrict__ cross, const float* __restrict__ htab,
    float* __restrict__ out)
{
    const int tid  = threadIdx.x;
    const int wave = tid >> 6;
    const int lane = tid & 63;
    const int r = blockIdx.x * 4 + wave;     // 0..40959 = b*10 + t
    const int b = r / NT;
    const int t = r - b * NT;

    float v = 0.f;
    if (lane < NL) v = cross[(size_t)b * (NT * NL) + t * NL + lane];
    unsigned long long m = __ballot(v > 0.5f);
    int leaf = m ? (int)__builtin_ctzll(m) : 0;
    int p = t * NL + leaf;

    const float4* h4 = (const float4*)htab;
    float4* o4 = (float4*)out;
    o4[(size_t)r * 64 + lane] = h4[(size_t)p * 64 + lane];
}

// ---------------------------------------------------------------------------
extern "C" void kernel_launch(void* const* d_in, const int* in_sizes, int n_in,
                              void* d_out, int out_size, void* d_ws, size_t ws_size,
                              hipStream_t stream)
{
    const float* cross = (const float*)d_in[0];
    const float* emb   = (const float*)d_in[1];
    const float* Wih   = (const float*)d_in[2];
    const float* Whh   = (const float*)d_in[3];
    const float* bih   = (const float*)d_in[4];
    const float* bhh   = (const float*)d_in[5];
    float* out = (float*)d_out;

    float* ws  = (float*)d_ws;
    float* xg  = ws;                         // 310*1024
    float* h1g = xg + NNODES * G4;           // 160*256 each
    float* h2g = h1g + NPATH * DD;
    float* h3g = h2g + NPATH * DD;
    float* h4g = h3g + NPATH * DD;

    hipLaunchKernelGGL(k_nodeproj, dim3(256), dim3(256), 0, stream,
                       emb, Wih, bih, bhh, xg);
    hipLaunchKernelGGL(k_steps, dim3(256), dim3(256), 0, stream,
                       xg, Whh, h1g, h2g, h3g, h4g);
    hipLaunchKernelGGL(k_scatter, dim3(10240), dim3(256), 0, stream,
                       cross, h4g, out);
}